// Round 4
// baseline (703.663 us; speedup 1.0000x reference)
//
#include <hip/hip_runtime.h>
#include <hip/hip_fp16.h>

#define B_ 16
#define M_ 1024
#define N_ 4096
#define H_ 128
#define CIN_ 67

typedef _Float16 half8 __attribute__((ext_vector_type(8)));
typedef _Float16 half4_t __attribute__((ext_vector_type(4)));
typedef float f32x4 __attribute__((ext_vector_type(4)));

// ---------------------------------------------------------------------------
// P0: q = BN(cent @ Wq^T), k = BN(feat @ Wk^T), output fp16.
// ---------------------------------------------------------------------------
#define SPA 104  // 96 + 8 pad, in halfs (row stride)

__global__ __launch_bounds__(256) void k_embed(
    const float* __restrict__ cent, const float* __restrict__ feat,
    const float* __restrict__ Wq, const float* __restrict__ Wk,
    const float* __restrict__ gq, const float* __restrict__ bq,
    const float* __restrict__ mq, const float* __restrict__ vq,
    const float* __restrict__ gk, const float* __restrict__ bk,
    const float* __restrict__ mk, const float* __restrict__ vk,
    __half* __restrict__ q16, __half* __restrict__ k16)
{
  __shared__ __align__(16) __half al[128 * SPA];
  __shared__ __align__(16) __half wl[128 * SPA];
  __shared__ float scl[128], shl[128];

  const int tid = threadIdx.x;
  const int wg  = blockIdx.x;
  const bool isq = (wg < 128);
  const int row0 = isq ? wg * 128 : (wg - 128) * 128;
  const float* in = isq ? cent : feat;
  const float* W  = isq ? Wq : Wk;
  const float* g  = isq ? gq : gk;
  const float* bb = isq ? bq : bk;
  const float* mm = isq ? mq : mk;
  const float* vv = isq ? vq : vk;
  __half* outp = isq ? q16 : k16;

  for (int i = tid; i < 128 * 29; i += 256) {
    int r = i / 29, c = 67 + (i - r * 29);
    al[r * SPA + c] = __float2half(0.f);
    wl[r * SPA + c] = __float2half(0.f);
  }
  for (int i = tid; i < 128 * CIN_; i += 256) {
    int r = i / CIN_, c = i - r * CIN_;
    al[r * SPA + c] = __float2half(in[(size_t)row0 * CIN_ + i]);
    wl[r * SPA + c] = __float2half(W[i]);
  }
  if (tid < 128) {
    float s = g[tid] * rsqrtf(vv[tid] + 1e-5f);
    scl[tid] = s;
    shl[tid] = bb[tid] - mm[tid] * s;
  }
  __syncthreads();

  const int lane = tid & 63, wv = tid >> 6;
  const int col = lane & 15, quad = lane >> 4;

  f32x4 acc[2][8];
#pragma unroll
  for (int ms = 0; ms < 2; ++ms)
#pragma unroll
    for (int ns = 0; ns < 8; ++ns) acc[ms][ns] = (f32x4){0.f, 0.f, 0.f, 0.f};

#pragma unroll
  for (int kk = 0; kk < 3; ++kk) {
    half8 af[2], bf[8];
#pragma unroll
    for (int ms = 0; ms < 2; ++ms)
      af[ms] = *(const half8*)&al[(wv * 32 + ms * 16 + col) * SPA + kk * 32 + quad * 8];
#pragma unroll
    for (int ns = 0; ns < 8; ++ns)
      bf[ns] = *(const half8*)&wl[(ns * 16 + col) * SPA + kk * 32 + quad * 8];
#pragma unroll
    for (int ms = 0; ms < 2; ++ms)
#pragma unroll
      for (int ns = 0; ns < 8; ++ns)
        acc[ms][ns] = __builtin_amdgcn_mfma_f32_16x16x32_f16(af[ms], bf[ns], acc[ms][ns], 0, 0, 0);
  }

#pragma unroll
  for (int ms = 0; ms < 2; ++ms)
#pragma unroll
    for (int reg = 0; reg < 4; ++reg) {
      int r = wv * 32 + ms * 16 + quad * 4 + reg;
#pragma unroll
      for (int ns = 0; ns < 8; ++ns) {
        int h = ns * 16 + col;
        float v = acc[ms][ns][reg] * scl[h] + shl[h];
        outp[(size_t)(row0 + r) * H_ + h] = __float2half(v);
      }
    }
}

// ---------------------------------------------------------------------------
// P1: Z[b,m] = sum_n exp(q.k). No row max (logits sigma ~9.3, max ~56 << 88).
// NO LDS, NO BARRIERS: per-wave q fragments live in 16 VGPRs across the whole
// strip; k fragments double-buffered straight from L2 (k16 is 1MB/batch,
// L2-resident). Waves free-run; occupancy limited only by VGPRs.
// ---------------------------------------------------------------------------
#define A1_STEP(KK, CUR, NXT, PRE)                                          \
  {                                                                         \
    if (PRE) {                                                              \
      _Pragma("unroll")                                                     \
      for (int nb = 0; nb < 8; ++nb)                                        \
        NXT[nb] = *(const half8*)(kt + (size_t)(nb * 16 + col) * H_ +       \
                                  ((KK) + 1) * 32 + quad * 8);              \
    }                                                                       \
    _Pragma("unroll")                                                       \
    for (int ms = 0; ms < 2; ++ms)                                          \
      _Pragma("unroll")                                                     \
      for (int nb = 0; nb < 8; ++nb)                                        \
        acc[ms][nb] = __builtin_amdgcn_mfma_f32_16x16x32_f16(               \
            qf[KK][ms], CUR[nb], acc[ms][nb], 0, 0, 0);                     \
  }

__global__ __launch_bounds__(256, 3) void k_attn1(
    const __half* __restrict__ q16, const __half* __restrict__ k16,
    float* __restrict__ Z)
{
  const int tid = threadIdx.x;
  const int b = blockIdx.z, mt = blockIdx.y, ns = blockIdx.x;
  const int m0 = mt * 128;
  const int lane = tid & 63, wv = tid >> 6;
  const int col = lane & 15, quad = lane >> 4;

  // persistent per-wave A fragments (q rows m0+wv*32+ms*16+col)
  half8 qf[4][2];
  {
    const __half* qb = q16 + ((size_t)(b * M_) + m0 + wv * 32 + col) * H_;
#pragma unroll
    for (int kk = 0; kk < 4; ++kk)
#pragma unroll
      for (int ms = 0; ms < 2; ++ms)
        qf[kk][ms] = *(const half8*)(qb + (size_t)ms * 16 * H_ + kk * 32 + quad * 8);
  }

  float zacc[8];
#pragma unroll
  for (int i = 0; i < 8; ++i) zacc[i] = 0.f;

  const __half* kstrip = k16 + ((size_t)(b * N_) + ns * 512) * H_;

  for (int t = 0; t < 4; ++t) {  // 4 k-tiles of 128 per strip
    const __half* kt = kstrip + (size_t)t * 128 * H_;

    f32x4 acc[2][8];
#pragma unroll
    for (int ms = 0; ms < 2; ++ms)
#pragma unroll
      for (int nb = 0; nb < 8; ++nb) acc[ms][nb] = (f32x4){0.f, 0.f, 0.f, 0.f};

    half8 bfA[8], bfB[8];
#pragma unroll
    for (int nb = 0; nb < 8; ++nb)
      bfA[nb] = *(const half8*)(kt + (size_t)(nb * 16 + col) * H_ + quad * 8);

    A1_STEP(0, bfA, bfB, 1)
    A1_STEP(1, bfB, bfA, 1)
    A1_STEP(2, bfA, bfB, 1)
    A1_STEP(3, bfB, bfA, 0)

#pragma unroll
    for (int ms = 0; ms < 2; ++ms)
#pragma unroll
      for (int reg = 0; reg < 4; ++reg) {
        float s = 0.f;
#pragma unroll
        for (int nb = 0; nb < 8; ++nb) s += __expf(acc[ms][nb][reg]);
        zacc[ms * 4 + reg] += s;
      }
  }

#pragma unroll
  for (int i = 0; i < 8; ++i) {
    zacc[i] += __shfl_xor(zacc[i], 1);
    zacc[i] += __shfl_xor(zacc[i], 2);
    zacc[i] += __shfl_xor(zacc[i], 4);
    zacc[i] += __shfl_xor(zacc[i], 8);
  }
  if (col == 0) {
#pragma unroll
    for (int i = 0; i < 8; ++i) {
      int m = m0 + wv * 32 + (i >> 2) * 16 + quad * 4 + (i & 3);
      atomicAdd(&Z[(size_t)b * M_ + m], zacc[i]);
    }
  }
}

// ---------------------------------------------------------------------------
// P3: logits GEMM (A=k per-wave regs, B=q double-buffered from L2; NO LDS,
// NO BARRIERS) + masked p = exp(x - lnZ) + t=sqrt((mask+1e-9)(p+1e-9))-1e-9
// -> fp16 t, and column-sum via global atomics.
// ---------------------------------------------------------------------------
#define A3_STEP(KK, CUR, NXT, PRE)                                          \
  {                                                                         \
    if (PRE) {                                                              \
      _Pragma("unroll")                                                     \
      for (int nb = 0; nb < 8; ++nb)                                        \
        NXT[nb] = *(const half8*)(qb + (size_t)(nb * 16 + col) * H_ +       \
                                  ((KK) + 1) * 32 + quad * 8);              \
    }                                                                       \
    _Pragma("unroll")                                                       \
    for (int ms = 0; ms < 2; ++ms)                                          \
      _Pragma("unroll")                                                     \
      for (int nb = 0; nb < 8; ++nb)                                        \
        acc[ms][nb] = __builtin_amdgcn_mfma_f32_16x16x32_f16(               \
            kf[KK][ms], CUR[nb], acc[ms][nb], 0, 0, 0);                     \
  }

__global__ __launch_bounds__(256, 3) void k_attn3(
    const __half* __restrict__ q16, const __half* __restrict__ k16,
    const float* __restrict__ mask, const float* __restrict__ Z,
    __half* __restrict__ t16, float* __restrict__ colsum)
{
  const int tid = threadIdx.x;
  const int b = blockIdx.z, mt = blockIdx.y, nt = blockIdx.x;
  const int m0 = mt * 128, n0 = nt * 128;
  const int lane = tid & 63, wv = tid >> 6;
  const int col = lane & 15, quad = lane >> 4;

  // per-wave A fragments (k rows n0+wv*32+ms*16+col)
  half8 kf[4][2];
  {
    const __half* kb = k16 + ((size_t)(b * N_) + n0 + wv * 32 + col) * H_;
#pragma unroll
    for (int kk = 0; kk < 4; ++kk)
#pragma unroll
      for (int ms = 0; ms < 2; ++ms)
        kf[kk][ms] = *(const half8*)(kb + (size_t)ms * 16 * H_ + kk * 32 + quad * 8);
  }

  // lnZ for the 8 m-rows this lane's epilogue touches (ml = nsm*16+col)
  float lz[8];
#pragma unroll
  for (int nsm = 0; nsm < 8; ++nsm)
    lz[nsm] = __logf(Z[(size_t)b * M_ + m0 + nsm * 16 + col]);

  // acc[msN][ns_m]: rows (quad*4+reg) = n-local, cols (col) = m-local
  f32x4 acc[2][8];
#pragma unroll
  for (int ms = 0; ms < 2; ++ms)
#pragma unroll
    for (int nb = 0; nb < 8; ++nb) acc[ms][nb] = (f32x4){0.f, 0.f, 0.f, 0.f};

  const __half* qb = q16 + ((size_t)(b * M_) + m0) * H_;
  half8 bfA[8], bfB[8];
#pragma unroll
  for (int nb = 0; nb < 8; ++nb)
    bfA[nb] = *(const half8*)(qb + (size_t)(nb * 16 + col) * H_ + quad * 8);

  A3_STEP(0, bfA, bfB, 1)
  A3_STEP(1, bfB, bfA, 1)
  A3_STEP(2, bfA, bfB, 1)
  A3_STEP(3, bfB, bfA, 0)

  float cs[8];  // n-slot sums: index = msN*4 + reg
#pragma unroll
  for (int i = 0; i < 8; ++i) cs[i] = 0.f;

#pragma unroll
  for (int msN = 0; msN < 2; ++msN) {
    const int nb = n0 + wv * 32 + msN * 16 + quad * 4;  // 4 consecutive n
#pragma unroll
    for (int nsm = 0; nsm < 8; ++nsm) {
      const int ml = nsm * 16 + col;
      const int m = m0 + ml;
      const float lzv = lz[nsm];
      const size_t base = ((size_t)b * M_ + m) * N_ + nb;
      const float4 mv = *(const float4*)&mask[base];
      half4_t h;
#pragma unroll
      for (int reg = 0; reg < 4; ++reg) {
        float mvv = (reg == 0) ? mv.x : (reg == 1) ? mv.y : (reg == 2) ? mv.z : mv.w;
        float x = acc[msN][nsm][reg];
        x = (mvv < 1e-9f) ? -1e9f : x;
        float p = __expf(x - lzv);
        float t = sqrtf((mvv + 1e-9f) * (p + 1e-9f)) - 1e-9f;
        h[reg] = (_Float16)t;
        cs[msN * 4 + reg] += t;
      }
      *(half4_t*)&t16[base] = h;
    }
  }
#pragma unroll
  for (int i = 0; i < 8; ++i) {
    cs[i] += __shfl_xor(cs[i], 1);
    cs[i] += __shfl_xor(cs[i], 2);
    cs[i] += __shfl_xor(cs[i], 4);
    cs[i] += __shfl_xor(cs[i], 8);
  }
  if (col == 0) {
#pragma unroll
    for (int i = 0; i < 8; ++i) {
      int n = n0 + wv * 32 + (i >> 2) * 16 + quad * 4 + (i & 3);
      atomicAdd(&colsum[(size_t)b * N_ + n], cs[i]);
    }
  }
}

// ---------------------------------------------------------------------------
// P3.5: invert colsum in place (replaces 67M divides in k_norm with muls).
// ---------------------------------------------------------------------------
__global__ __launch_bounds__(256) void k_icol(float* __restrict__ cs)
{
  int i = blockIdx.x * 256 + threadIdx.x;
  cs[i] = 1.f / fmaxf(cs[i], 1e-12f);
}

// ---------------------------------------------------------------------------
// P4: u = t * icolsum; out = u / max(rowsum(u),1e-12).
// t is fp16 in ws; out is fp32 d_out. One wg per (b,m) row.
// ---------------------------------------------------------------------------
__global__ __launch_bounds__(256) void k_norm(
    const __half* __restrict__ t16, float* __restrict__ out,
    const float* __restrict__ icol)
{
  const int row = blockIdx.x;
  const int b = row >> 10;
  const half4_t* t4 = (const half4_t*)(t16 + (size_t)row * N_);
  float4* o4 = (float4*)(out + (size_t)row * N_);
  const float4* c4 = (const float4*)(icol + (size_t)b * N_);
  const int tid = threadIdx.x;

  float4 u[4];
  float s = 0.f;
#pragma unroll
  for (int j = 0; j < 4; ++j) {
    int idx = tid + 256 * j;
    half4_t h = t4[idx];
    float4 c = c4[idx];
    u[j].x = (float)h[0] * c.x;
    u[j].y = (float)h[1] * c.y;
    u[j].z = (float)h[2] * c.z;
    u[j].w = (float)h[3] * c.w;
    s += u[j].x + u[j].y + u[j].z + u[j].w;  // t >= 0 so |u| = u
  }
  s += __shfl_xor(s, 1);
  s += __shfl_xor(s, 2);
  s += __shfl_xor(s, 4);
  s += __shfl_xor(s, 8);
  s += __shfl_xor(s, 16);
  s += __shfl_xor(s, 32);
  __shared__ float red[4];
  if ((tid & 63) == 0) red[tid >> 6] = s;
  __syncthreads();
  float tot = red[0] + red[1] + red[2] + red[3];
  float inv = 1.f / fmaxf(tot, 1e-12f);
#pragma unroll
  for (int j = 0; j < 4; ++j) {
    int idx = tid + 256 * j;
    float4 v = u[j];
    v.x *= inv; v.y *= inv; v.z *= inv; v.w *= inv;
    o4[idx] = v;
  }
}

// ---------------------------------------------------------------------------
extern "C" void kernel_launch(void* const* d_in, const int* in_sizes, int n_in,
                              void* d_out, int out_size, void* d_ws, size_t ws_size,
                              hipStream_t stream) {
  const float* cent = (const float*)d_in[0];
  const float* feat = (const float*)d_in[1];
  const float* mask = (const float*)d_in[2];
  const float* Wq = (const float*)d_in[3];
  const float* Wk = (const float*)d_in[4];
  const float* gq = (const float*)d_in[5];
  const float* bq = (const float*)d_in[6];
  const float* mq = (const float*)d_in[7];
  const float* vq = (const float*)d_in[8];
  const float* gk = (const float*)d_in[9];
  const float* bk = (const float*)d_in[10];
  const float* mk = (const float*)d_in[11];
  const float* vk = (const float*)d_in[12];
  float* out = (float*)d_out;

  char* ws = (char*)d_ws;
  // workspace layout (bytes)
  __half* q16  = (__half*)(ws + 0);            //   4,194,304
  __half* k16  = (__half*)(ws + 4194304);      //  16,777,216
  __half* t16  = (__half*)(ws + 20971520);     // 134,217,728
  float* colsum= (float*)(ws + 155189248);     //     262,144
  float* Zr    = (float*)(ws + 155451392);     //      65,536

  // colsum + Z are contiguous: one memset clears both
  hipMemsetAsync(colsum, 0, 262144 + 65536, stream);

  k_embed<<<640, 256, 0, stream>>>(cent, feat, Wq, Wk, gq, bq, mq, vq,
                                   gk, bk, mk, vk, q16, k16);

  dim3 g1(8, 8, 16);  // n-strips of 512, mt, b -> 1024 wgs, barrier-free
  k_attn1<<<g1, 256, 0, stream>>>(q16, k16, Zr);

  dim3 g3(N_ / 128, M_ / 128, B_);  // (32, 8, 16)
  k_attn3<<<g3, 256, 0, stream>>>(q16, k16, mask, Zr, t16, colsum);
  k_icol<<<B_ * N_ / 256, 256, 0, stream>>>(colsum);
  k_norm<<<B_ * M_, 256, 0, stream>>>(t16, out, colsum);
}

// Round 5
// 638.397 us; speedup vs baseline: 1.1022x; 1.1022x over previous
//
#include <hip/hip_runtime.h>
#include <hip/hip_fp16.h>

#define B_ 16
#define M_ 1024
#define N_ 4096
#define H_ 128
#define CIN_ 67

typedef _Float16 half8 __attribute__((ext_vector_type(8)));
typedef _Float16 half4_t __attribute__((ext_vector_type(4)));
typedef float f32x4 __attribute__((ext_vector_type(4)));

// ---------------------------------------------------------------------------
// P0: q = BN(cent @ Wq^T), k = BN(feat @ Wk^T), output fp16.
// ---------------------------------------------------------------------------
#define SPA 104  // 96 + 8 pad, in halfs (row stride)

__global__ __launch_bounds__(256) void k_embed(
    const float* __restrict__ cent, const float* __restrict__ feat,
    const float* __restrict__ Wq, const float* __restrict__ Wk,
    const float* __restrict__ gq, const float* __restrict__ bq,
    const float* __restrict__ mq, const float* __restrict__ vq,
    const float* __restrict__ gk, const float* __restrict__ bk,
    const float* __restrict__ mk, const float* __restrict__ vk,
    __half* __restrict__ q16, __half* __restrict__ k16)
{
  __shared__ __align__(16) __half al[128 * SPA];
  __shared__ __align__(16) __half wl[128 * SPA];
  __shared__ float scl[128], shl[128];

  const int tid = threadIdx.x;
  const int wg  = blockIdx.x;
  const bool isq = (wg < 128);
  const int row0 = isq ? wg * 128 : (wg - 128) * 128;
  const float* in = isq ? cent : feat;
  const float* W  = isq ? Wq : Wk;
  const float* g  = isq ? gq : gk;
  const float* bb = isq ? bq : bk;
  const float* mm = isq ? mq : mk;
  const float* vv = isq ? vq : vk;
  __half* outp = isq ? q16 : k16;

  for (int i = tid; i < 128 * 29; i += 256) {
    int r = i / 29, c = 67 + (i - r * 29);
    al[r * SPA + c] = __float2half(0.f);
    wl[r * SPA + c] = __float2half(0.f);
  }
  for (int i = tid; i < 128 * CIN_; i += 256) {
    int r = i / CIN_, c = i - r * CIN_;
    al[r * SPA + c] = __float2half(in[(size_t)row0 * CIN_ + i]);
    wl[r * SPA + c] = __float2half(W[i]);
  }
  if (tid < 128) {
    float s = g[tid] * rsqrtf(vv[tid] + 1e-5f);
    scl[tid] = s;
    shl[tid] = bb[tid] - mm[tid] * s;
  }
  __syncthreads();

  const int lane = tid & 63, wv = tid >> 6;
  const int col = lane & 15, quad = lane >> 4;

  f32x4 acc[2][8];
#pragma unroll
  for (int ms = 0; ms < 2; ++ms)
#pragma unroll
    for (int ns = 0; ns < 8; ++ns) acc[ms][ns] = (f32x4){0.f, 0.f, 0.f, 0.f};

#pragma unroll
  for (int kk = 0; kk < 3; ++kk) {
    half8 af[2], bf[8];
#pragma unroll
    for (int ms = 0; ms < 2; ++ms)
      af[ms] = *(const half8*)&al[(wv * 32 + ms * 16 + col) * SPA + kk * 32 + quad * 8];
#pragma unroll
    for (int ns = 0; ns < 8; ++ns)
      bf[ns] = *(const half8*)&wl[(ns * 16 + col) * SPA + kk * 32 + quad * 8];
#pragma unroll
    for (int ms = 0; ms < 2; ++ms)
#pragma unroll
      for (int ns = 0; ns < 8; ++ns)
        acc[ms][ns] = __builtin_amdgcn_mfma_f32_16x16x32_f16(af[ms], bf[ns], acc[ms][ns], 0, 0, 0);
  }

#pragma unroll
  for (int ms = 0; ms < 2; ++ms)
#pragma unroll
    for (int reg = 0; reg < 4; ++reg) {
      int r = wv * 32 + ms * 16 + quad * 4 + reg;
#pragma unroll
      for (int ns = 0; ns < 8; ++ns) {
        int h = ns * 16 + col;
        float v = acc[ms][ns][reg] * scl[h] + shl[h];
        outp[(size_t)(row0 + r) * H_ + h] = __float2half(v);
      }
    }
}

// ---------------------------------------------------------------------------
// P1: Z[b,m] = sum_n exp(q.k). No row max (logits sigma ~9.3, max ~56 << 88).
// Hybrid staging: per-wave q fragments live in 32 VGPRs for the whole strip
// (loaded ONCE); k-tiles cooperatively staged into a single 35 KB LDS buffer;
// next tile's register-prefetch issued right after the write barrier so its
// HBM/L2 latency hides under the current tile's GEMM+exp.
// ---------------------------------------------------------------------------
#define SPB 136  // 128 + 8 pad, in halfs

__global__ __launch_bounds__(256, 3) void k_attn1(
    const __half* __restrict__ q16, const __half* __restrict__ k16,
    float* __restrict__ Z)
{
  __shared__ __align__(16) __half ka[128 * SPB];  // 34,816 B

  const int tid = threadIdx.x;
  const int b = blockIdx.z, mt = blockIdx.y, ns = blockIdx.x;
  const int m0 = mt * 128;
  const int lane = tid & 63, wv = tid >> 6;
  const int col = lane & 15, quad = lane >> 4;

  const __half* kstrip = k16 + ((size_t)(b * N_) + ns * 512) * H_;

  // issue tile-0 staging loads first (oldest in vmcnt queue)...
  uint4 kreg[8];
  {
    const uint4* srck0 = (const uint4*)kstrip;
#pragma unroll
    for (int j = 0; j < 8; ++j) kreg[j] = srck0[tid + 256 * j];
  }
  // ...then the loop-invariant per-wave q fragments (A operand)
  half8 qf[4][2];
  {
    const __half* qb = q16 + ((size_t)(b * M_) + m0 + wv * 32 + col) * H_;
#pragma unroll
    for (int kk = 0; kk < 4; ++kk)
#pragma unroll
      for (int ms = 0; ms < 2; ++ms)
        qf[kk][ms] = *(const half8*)(qb + (size_t)ms * 16 * H_ + kk * 32 + quad * 8);
  }

  float zacc[8];
#pragma unroll
  for (int i = 0; i < 8; ++i) zacc[i] = 0.f;

  for (int t = 0; t < 4; ++t) {  // 4 k-tiles of 128 per strip
    if (t) __syncthreads();  // previous GEMM's LDS readers must finish
#pragma unroll
    for (int j = 0; j < 8; ++j) {
      int i = tid + 256 * j;
      int r = i >> 4, c = i & 15;
      *(uint4*)&ka[r * SPB + c * 8] = kreg[j];
    }
    __syncthreads();
    if (t < 3) {  // prefetch next tile; drained by NEXT iteration's barrier
      const uint4* srck = (const uint4*)(kstrip + (size_t)(t + 1) * 128 * H_);
#pragma unroll
      for (int j = 0; j < 8; ++j) kreg[j] = srck[tid + 256 * j];
    }
    __builtin_amdgcn_sched_barrier(0);  // pin prefetch issue before GEMM

    f32x4 acc[2][8];
#pragma unroll
    for (int ms = 0; ms < 2; ++ms)
#pragma unroll
      for (int nb = 0; nb < 8; ++nb) acc[ms][nb] = (f32x4){0.f, 0.f, 0.f, 0.f};

#pragma unroll
    for (int kk = 0; kk < 4; ++kk) {
#pragma unroll
      for (int nb = 0; nb < 8; ++nb) {
        half8 bf = *(const half8*)&ka[(nb * 16 + col) * SPB + kk * 32 + quad * 8];
        acc[0][nb] = __builtin_amdgcn_mfma_f32_16x16x32_f16(qf[kk][0], bf, acc[0][nb], 0, 0, 0);
        acc[1][nb] = __builtin_amdgcn_mfma_f32_16x16x32_f16(qf[kk][1], bf, acc[1][nb], 0, 0, 0);
      }
    }

#pragma unroll
    for (int ms = 0; ms < 2; ++ms)
#pragma unroll
      for (int reg = 0; reg < 4; ++reg) {
        float s = 0.f;
#pragma unroll
        for (int nb = 0; nb < 8; ++nb) s += __expf(acc[ms][nb][reg]);
        zacc[ms * 4 + reg] += s;
      }
  }

#pragma unroll
  for (int i = 0; i < 8; ++i) {
    zacc[i] += __shfl_xor(zacc[i], 1);
    zacc[i] += __shfl_xor(zacc[i], 2);
    zacc[i] += __shfl_xor(zacc[i], 4);
    zacc[i] += __shfl_xor(zacc[i], 8);
  }
  if (col == 0) {
#pragma unroll
    for (int i = 0; i < 8; ++i) {
      int m = m0 + wv * 32 + (i >> 2) * 16 + quad * 4 + (i & 3);
      atomicAdd(&Z[(size_t)b * M_ + m], zacc[i]);
    }
  }
}

// ---------------------------------------------------------------------------
// P3: logits GEMM (A = per-wave k regs, B = q in 35 KB LDS) + masked
// p = exp(x - lnZ), t = sqrt((mask+1e-9)(p+1e-9))-1e-9 -> fp16 t + colsum.
// msN=0 mask half issued BEFORE the staging barrier (flies with qa/kf loads);
// msN=1 half issued at epilogue start (reuses dead kf registers).
// ---------------------------------------------------------------------------
__global__ __launch_bounds__(256, 3) void k_attn3(
    const __half* __restrict__ q16, const __half* __restrict__ k16,
    const float* __restrict__ mask, const float* __restrict__ Z,
    __half* __restrict__ t16, float* __restrict__ colsum)
{
  __shared__ __align__(16) __half qa[128 * SPB];  // 34,816 B

  const int tid = threadIdx.x;
  const int b = blockIdx.z, mt = blockIdx.y, nt = blockIdx.x;
  const int m0 = mt * 128, n0 = nt * 128;
  const int lane = tid & 63, wv = tid >> 6;
  const int col = lane & 15, quad = lane >> 4;

  // 1) q-tile staging loads (oldest in vmcnt queue)
  uint4 qreg[8];
  {
    const uint4* srcq = (const uint4*)(q16 + ((size_t)(b * M_) + m0) * H_);
#pragma unroll
    for (int j = 0; j < 8; ++j) qreg[j] = srcq[tid + 256 * j];
  }
  // 2) per-wave k fragments (A operand), L2-resident
  half8 kf[4][2];
  {
    const __half* kb = k16 + ((size_t)(b * N_) + n0 + wv * 32 + col) * H_;
#pragma unroll
    for (int kk = 0; kk < 4; ++kk)
#pragma unroll
      for (int ms = 0; ms < 2; ++ms)
        kf[kk][ms] = *(const half8*)(kb + (size_t)ms * 16 * H_ + kk * 32 + quad * 8);
  }
  // 3) raw Z for this lane's 8 m-rows (log taken in epilogue)
  float zr[8];
#pragma unroll
  for (int nsm = 0; nsm < 8; ++nsm)
    zr[nsm] = Z[(size_t)b * M_ + m0 + nsm * 16 + col];
  // 4) mask prefetch, msN=0 half — completes at the staging barrier's drain
  float4 mv0[8];
  {
    const int nb = n0 + wv * 32 + quad * 4;
#pragma unroll
    for (int nsm = 0; nsm < 8; ++nsm)
      mv0[nsm] = *(const float4*)&mask[((size_t)b * M_ + m0 + nsm * 16 + col) * N_ + nb];
  }
  __builtin_amdgcn_sched_barrier(0);  // pin all issues above this point

  // stage q-tile to LDS (waits only its own loads via counted vmcnt)
#pragma unroll
  for (int j = 0; j < 8; ++j) {
    int i = tid + 256 * j;
    int r = i >> 4, c = i & 15;
    *(uint4*)&qa[r * SPB + c * 8] = qreg[j];
  }
  __syncthreads();

  // GEMM: acc[ms][nb] — rows (quad*4+reg) = n-local, cols (col) = m-local
  f32x4 acc[2][8];
#pragma unroll
  for (int ms = 0; ms < 2; ++ms)
#pragma unroll
    for (int nb = 0; nb < 8; ++nb) acc[ms][nb] = (f32x4){0.f, 0.f, 0.f, 0.f};

#pragma unroll
  for (int kk = 0; kk < 4; ++kk) {
#pragma unroll
    for (int nb = 0; nb < 8; ++nb) {
      half8 bf = *(const half8*)&qa[(nb * 16 + col) * SPB + kk * 32 + quad * 8];
      acc[0][nb] = __builtin_amdgcn_mfma_f32_16x16x32_f16(kf[kk][0], bf, acc[0][nb], 0, 0, 0);
      acc[1][nb] = __builtin_amdgcn_mfma_f32_16x16x32_f16(kf[kk][1], bf, acc[1][nb], 0, 0, 0);
    }
  }

  // epilogue: issue msN=1 mask loads first (kf now dead — regs reused)
  float4 mv1[8];
  {
    const int nb = n0 + wv * 32 + 16 + quad * 4;
#pragma unroll
    for (int nsm = 0; nsm < 8; ++nsm)
      mv1[nsm] = *(const float4*)&mask[((size_t)b * M_ + m0 + nsm * 16 + col) * N_ + nb];
  }
  __builtin_amdgcn_sched_barrier(0);

#pragma unroll
  for (int i = 0; i < 8; ++i) zr[i] = __logf(zr[i]);

  float cs[8];  // n-slot sums: index = msN*4 + reg
#pragma unroll
  for (int i = 0; i < 8; ++i) cs[i] = 0.f;

#define EPI(MSN, MV)                                                        \
  {                                                                         \
    const int nb = n0 + wv * 32 + (MSN) * 16 + quad * 4;                    \
    _Pragma("unroll")                                                       \
    for (int nsm = 0; nsm < 8; ++nsm) {                                     \
      const int m = m0 + nsm * 16 + col;                                    \
      const float lzv = zr[nsm];                                            \
      const size_t base = ((size_t)b * M_ + m) * N_ + nb;                   \
      const float4 mv = MV[nsm];                                            \
      half4_t h;                                                            \
      _Pragma("unroll")                                                     \
      for (int reg = 0; reg < 4; ++reg) {                                   \
        float mvv = (reg == 0) ? mv.x : (reg == 1) ? mv.y                   \
                  : (reg == 2) ? mv.z : mv.w;                               \
        float x = acc[MSN][nsm][reg];                                       \
        x = (mvv < 1e-9f) ? -1e9f : x;                                      \
        float p = __expf(x - lzv);                                          \
        float t = sqrtf((mvv + 1e-9f) * (p + 1e-9f)) - 1e-9f;               \
        h[reg] = (_Float16)t;                                               \
        cs[(MSN) * 4 + reg] += t;                                           \
      }                                                                     \
      *(half4_t*)&t16[base] = h;                                            \
    }                                                                       \
  }

  EPI(0, mv0)
  EPI(1, mv1)
#undef EPI

#pragma unroll
  for (int i = 0; i < 8; ++i) {
    cs[i] += __shfl_xor(cs[i], 1);
    cs[i] += __shfl_xor(cs[i], 2);
    cs[i] += __shfl_xor(cs[i], 4);
    cs[i] += __shfl_xor(cs[i], 8);
  }
  if (col == 0) {
#pragma unroll
    for (int i = 0; i < 8; ++i) {
      int n = n0 + wv * 32 + (i >> 2) * 16 + quad * 4 + (i & 3);
      atomicAdd(&colsum[(size_t)b * N_ + n], cs[i]);
    }
  }
}

// ---------------------------------------------------------------------------
// P3.5: invert colsum in place (replaces 67M divides in k_norm with muls).
// ---------------------------------------------------------------------------
__global__ __launch_bounds__(256) void k_icol(float* __restrict__ cs)
{
  int i = blockIdx.x * 256 + threadIdx.x;
  cs[i] = 1.f / fmaxf(cs[i], 1e-12f);
}

// ---------------------------------------------------------------------------
// P4: u = t * icolsum; out = u / max(rowsum(u),1e-12).
// ---------------------------------------------------------------------------
__global__ __launch_bounds__(256) void k_norm(
    const __half* __restrict__ t16, float* __restrict__ out,
    const float* __restrict__ icol)
{
  const int row = blockIdx.x;
  const int b = row >> 10;
  const half4_t* t4 = (const half4_t*)(t16 + (size_t)row * N_);
  float4* o4 = (float4*)(out + (size_t)row * N_);
  const float4* c4 = (const float4*)(icol + (size_t)b * N_);
  const int tid = threadIdx.x;

  float4 u[4];
  float s = 0.f;
#pragma unroll
  for (int j = 0; j < 4; ++j) {
    int idx = tid + 256 * j;
    half4_t h = t4[idx];
    float4 c = c4[idx];
    u[j].x = (float)h[0] * c.x;
    u[j].y = (float)h[1] * c.y;
    u[j].z = (float)h[2] * c.z;
    u[j].w = (float)h[3] * c.w;
    s += u[j].x + u[j].y + u[j].z + u[j].w;  // t >= 0 so |u| = u
  }
  s += __shfl_xor(s, 1);
  s += __shfl_xor(s, 2);
  s += __shfl_xor(s, 4);
  s += __shfl_xor(s, 8);
  s += __shfl_xor(s, 16);
  s += __shfl_xor(s, 32);
  __shared__ float red[4];
  if ((tid & 63) == 0) red[tid >> 6] = s;
  __syncthreads();
  float tot = red[0] + red[1] + red[2] + red[3];
  float inv = 1.f / fmaxf(tot, 1e-12f);
#pragma unroll
  for (int j = 0; j < 4; ++j) {
    int idx = tid + 256 * j;
    float4 v = u[j];
    v.x *= inv; v.y *= inv; v.z *= inv; v.w *= inv;
    o4[idx] = v;
  }
}

// ---------------------------------------------------------------------------
extern "C" void kernel_launch(void* const* d_in, const int* in_sizes, int n_in,
                              void* d_out, int out_size, void* d_ws, size_t ws_size,
                              hipStream_t stream) {
  const float* cent = (const float*)d_in[0];
  const float* feat = (const float*)d_in[1];
  const float* mask = (const float*)d_in[2];
  const float* Wq = (const float*)d_in[3];
  const float* Wk = (const float*)d_in[4];
  const float* gq = (const float*)d_in[5];
  const float* bq = (const float*)d_in[6];
  const float* mq = (const float*)d_in[7];
  const float* vq = (const float*)d_in[8];
  const float* gk = (const float*)d_in[9];
  const float* bk = (const float*)d_in[10];
  const float* mk = (const float*)d_in[11];
  const float* vk = (const float*)d_in[12];
  float* out = (float*)d_out;

  char* ws = (char*)d_ws;
  // workspace layout (bytes)
  __half* q16  = (__half*)(ws + 0);            //   4,194,304
  __half* k16  = (__half*)(ws + 4194304);      //  16,777,216
  __half* t16  = (__half*)(ws + 20971520);     // 134,217,728
  float* colsum= (float*)(ws + 155189248);     //     262,144
  float* Zr    = (float*)(ws + 155451392);     //      65,536

  // colsum + Z are contiguous: one memset clears both
  hipMemsetAsync(colsum, 0, 262144 + 65536, stream);

  k_embed<<<640, 256, 0, stream>>>(cent, feat, Wq, Wk, gq, bq, mq, vq,
                                   gk, bk, mk, vk, q16, k16);

  dim3 g1(8, 8, 16);  // n-strips of 512 (4 tiles), mt, b -> 1024 wgs
  k_attn1<<<g1, 256, 0, stream>>>(q16, k16, Zr);

  dim3 g3(N_ / 128, M_ / 128, B_);  // (32, 8, 16)
  k_attn3<<<g3, 256, 0, stream>>>(q16, k16, mask, Zr, t16, colsum);
  k_icol<<<B_ * N_ / 256, 256, 0, stream>>>(colsum);
  k_norm<<<B_ * M_, 256, 0, stream>>>(t16, out, colsum);
}

// Round 6
// 618.399 us; speedup vs baseline: 1.1379x; 1.0323x over previous
//
#include <hip/hip_runtime.h>
#include <hip/hip_fp16.h>

#define B_ 16
#define M_ 1024
#define N_ 4096
#define H_ 128
#define CIN_ 67

typedef _Float16 half8 __attribute__((ext_vector_type(8)));
typedef _Float16 half4_t __attribute__((ext_vector_type(4)));
typedef float f32x4 __attribute__((ext_vector_type(4)));

// ---------------------------------------------------------------------------
// P0: q = BN(cent @ Wq^T) * log2(e)  [log2-domain logits], k = BN(feat @ Wk^T).
// ---------------------------------------------------------------------------
#define SPA 104  // 96 + 8 pad, in halfs (row stride)

__global__ __launch_bounds__(256) void k_embed(
    const float* __restrict__ cent, const float* __restrict__ feat,
    const float* __restrict__ Wq, const float* __restrict__ Wk,
    const float* __restrict__ gq, const float* __restrict__ bq,
    const float* __restrict__ mq, const float* __restrict__ vq,
    const float* __restrict__ gk, const float* __restrict__ bk,
    const float* __restrict__ mk, const float* __restrict__ vk,
    __half* __restrict__ q16, __half* __restrict__ k16)
{
  __shared__ __align__(16) __half al[128 * SPA];
  __shared__ __align__(16) __half wl[128 * SPA];
  __shared__ float scl[128], shl[128];

  const int tid = threadIdx.x;
  const int wg  = blockIdx.x;
  const bool isq = (wg < 128);
  const int row0 = isq ? wg * 128 : (wg - 128) * 128;
  const float* in = isq ? cent : feat;
  const float* W  = isq ? Wq : Wk;
  const float* g  = isq ? gq : gk;
  const float* bb = isq ? bq : bk;
  const float* mm = isq ? mq : mk;
  const float* vv = isq ? vq : vk;
  __half* outp = isq ? q16 : k16;

  for (int i = tid; i < 128 * 29; i += 256) {
    int r = i / 29, c = 67 + (i - r * 29);
    al[r * SPA + c] = __float2half(0.f);
    wl[r * SPA + c] = __float2half(0.f);
  }
  for (int i = tid; i < 128 * CIN_; i += 256) {
    int r = i / CIN_, c = i - r * CIN_;
    al[r * SPA + c] = __float2half(in[(size_t)row0 * CIN_ + i]);
    wl[r * SPA + c] = __float2half(W[i]);
  }
  if (tid < 128) {
    float s = g[tid] * rsqrtf(vv[tid] + 1e-5f);
    float sc = isq ? 1.44269504088896f : 1.f;  // fold log2(e) into q
    scl[tid] = s * sc;
    shl[tid] = (bb[tid] - mm[tid] * s) * sc;
  }
  __syncthreads();

  const int lane = tid & 63, wv = tid >> 6;
  const int col = lane & 15, quad = lane >> 4;

  f32x4 acc[2][8];
#pragma unroll
  for (int ms = 0; ms < 2; ++ms)
#pragma unroll
    for (int ns = 0; ns < 8; ++ns) acc[ms][ns] = (f32x4){0.f, 0.f, 0.f, 0.f};

#pragma unroll
  for (int kk = 0; kk < 3; ++kk) {
    half8 af[2], bf[8];
#pragma unroll
    for (int ms = 0; ms < 2; ++ms)
      af[ms] = *(const half8*)&al[(wv * 32 + ms * 16 + col) * SPA + kk * 32 + quad * 8];
#pragma unroll
    for (int ns = 0; ns < 8; ++ns)
      bf[ns] = *(const half8*)&wl[(ns * 16 + col) * SPA + kk * 32 + quad * 8];
#pragma unroll
    for (int ms = 0; ms < 2; ++ms)
#pragma unroll
      for (int ns = 0; ns < 8; ++ns)
        acc[ms][ns] = __builtin_amdgcn_mfma_f32_16x16x32_f16(af[ms], bf[ns], acc[ms][ns], 0, 0, 0);
  }

#pragma unroll
  for (int ms = 0; ms < 2; ++ms)
#pragma unroll
    for (int reg = 0; reg < 4; ++reg) {
      int r = wv * 32 + ms * 16 + quad * 4 + reg;
#pragma unroll
      for (int ns = 0; ns < 8; ++ns) {
        int h = ns * 16 + col;
        float v = acc[ms][ns][reg] * scl[h] + shl[h];
        outp[(size_t)(row0 + r) * H_ + h] = __float2half(v);
      }
    }
}

// ---------------------------------------------------------------------------
// P1: Z[b,m] = sum_n 2^(q.k). Logits are log2-domain (q pre-scaled), so the
// exp is a bare v_exp_f32. No row max (x2 <= ~81 << 127). Padded-LDS k-tile
// staging (34.8 KB -> 4 wgs/CU at launch_bounds(256,4)); next tile prefetched
// in two 4xuint4 batches interleaved with the exp-epilogue halves.
// ---------------------------------------------------------------------------
#define SPB 136  // 128 + 8 pad, in halfs

__global__ __launch_bounds__(256, 4) void k_attn1(
    const __half* __restrict__ q16, const __half* __restrict__ k16,
    float* __restrict__ Z)
{
  __shared__ __align__(16) __half ka[128 * SPB];  // 34,816 B

  const int tid = threadIdx.x;
  const int b = blockIdx.z, mt = blockIdx.y, ns = blockIdx.x;
  const int m0 = mt * 128;
  const int lane = tid & 63, wv = tid >> 6;
  const int col = lane & 15, quad = lane >> 4;

  const __half* kstrip = k16 + ((size_t)(b * N_) + ns * 512) * H_;

  // stage tile 0
  {
    uint4 kr[8];
    const uint4* s0 = (const uint4*)kstrip;
#pragma unroll
    for (int j = 0; j < 8; ++j) kr[j] = s0[tid + 256 * j];
#pragma unroll
    for (int j = 0; j < 8; ++j) {
      int i = tid + 256 * j;
      *(uint4*)&ka[(i >> 4) * SPB + (i & 15) * 8] = kr[j];
    }
  }
  // loop-invariant per-wave q fragments (A operand)
  half8 qf[4][2];
  {
    const __half* qb = q16 + ((size_t)(b * M_) + m0 + wv * 32 + col) * H_;
#pragma unroll
    for (int kk = 0; kk < 4; ++kk)
#pragma unroll
      for (int ms = 0; ms < 2; ++ms)
        qf[kk][ms] = *(const half8*)(qb + (size_t)ms * 16 * H_ + kk * 32 + quad * 8);
  }
  __syncthreads();

  float zacc[8];
#pragma unroll
  for (int i = 0; i < 8; ++i) zacc[i] = 0.f;

  for (int t = 0; t < 4; ++t) {
    f32x4 acc[2][8];
#pragma unroll
    for (int ms = 0; ms < 2; ++ms)
#pragma unroll
      for (int nb = 0; nb < 8; ++nb) acc[ms][nb] = (f32x4){0.f, 0.f, 0.f, 0.f};

#pragma unroll
    for (int kk = 0; kk < 4; ++kk) {
#pragma unroll
      for (int nb = 0; nb < 8; ++nb) {
        half8 bf = *(const half8*)&ka[(nb * 16 + col) * SPB + kk * 32 + quad * 8];
        acc[0][nb] = __builtin_amdgcn_mfma_f32_16x16x32_f16(qf[kk][0], bf, acc[0][nb], 0, 0, 0);
        acc[1][nb] = __builtin_amdgcn_mfma_f32_16x16x32_f16(qf[kk][1], bf, acc[1][nb], 0, 0, 0);
      }
    }

    const uint4* sn = (const uint4*)(kstrip + (size_t)(t + 1) * 128 * H_);
    uint4 kr2[4];
    if (t < 3) {
      __syncthreads();  // all LDS reads of tile t done
#pragma unroll
      for (int j = 0; j < 4; ++j) kr2[j] = sn[tid + 256 * j];
    }

    // epilogue half A (ms=0) — covers batch-1 load latency
#pragma unroll
    for (int reg = 0; reg < 4; ++reg) {
      float s = 0.f;
#pragma unroll
      for (int nb = 0; nb < 8; ++nb) s += exp2f(acc[0][nb][reg]);
      zacc[reg] += s;
    }

    if (t < 3) {
#pragma unroll
      for (int j = 0; j < 4; ++j) {
        int i = tid + 256 * j;
        *(uint4*)&ka[(i >> 4) * SPB + (i & 15) * 8] = kr2[j];
      }
#pragma unroll
      for (int j = 0; j < 4; ++j) kr2[j] = sn[tid + 256 * (j + 4)];
    }

    // epilogue half B (ms=1) — covers batch-2 load latency
#pragma unroll
    for (int reg = 0; reg < 4; ++reg) {
      float s = 0.f;
#pragma unroll
      for (int nb = 0; nb < 8; ++nb) s += exp2f(acc[1][nb][reg]);
      zacc[4 + reg] += s;
    }

    if (t < 3) {
#pragma unroll
      for (int j = 0; j < 4; ++j) {
        int i = tid + 256 * (j + 4);
        *(uint4*)&ka[(i >> 4) * SPB + (i & 15) * 8] = kr2[j];
      }
      __syncthreads();  // tile t+1 staged
    }
  }

#pragma unroll
  for (int i = 0; i < 8; ++i) {
    zacc[i] += __shfl_xor(zacc[i], 1);
    zacc[i] += __shfl_xor(zacc[i], 2);
    zacc[i] += __shfl_xor(zacc[i], 4);
    zacc[i] += __shfl_xor(zacc[i], 8);
  }
  if (col == 0) {
#pragma unroll
    for (int i = 0; i < 8; ++i) {
      int m = m0 + wv * 32 + (i >> 2) * 16 + quad * 4 + (i & 3);
      atomicAdd(&Z[(size_t)b * M_ + m], zacc[i]);
    }
  }
}

// ---------------------------------------------------------------------------
// P3: logits GEMM (A=k per-wave regs, B=q in padded LDS) + masked
// p = 2^(x - log2Z), t = sqrt((mask+1e-9)(p+1e-9))-1e-9 -> t16 + colsum.
// t-tile is TRANSPOSED through the dead qa buffer: scattered half4 LDS
// writes (2-way conflict), then fully-coalesced 256B-row global stores.
// ---------------------------------------------------------------------------
__global__ __launch_bounds__(256, 4) void k_attn3(
    const __half* __restrict__ q16, const __half* __restrict__ k16,
    const float* __restrict__ mask, const float* __restrict__ Z,
    __half* __restrict__ t16, float* __restrict__ colsum)
{
  __shared__ __align__(16) __half qa[128 * SPB];  // 34,816 B; reused for t

  const int tid = threadIdx.x;
  const int b = blockIdx.z, mt = blockIdx.y, nt = blockIdx.x;
  const int m0 = mt * 128, n0 = nt * 128;
  const int lane = tid & 63, wv = tid >> 6;
  const int col = lane & 15, quad = lane >> 4;

  // stage q-tile
  {
    uint4 qr[8];
    const uint4* sq = (const uint4*)(q16 + ((size_t)(b * M_) + m0) * H_);
#pragma unroll
    for (int j = 0; j < 8; ++j) qr[j] = sq[tid + 256 * j];
#pragma unroll
    for (int j = 0; j < 8; ++j) {
      int i = tid + 256 * j;
      *(uint4*)&qa[(i >> 4) * SPB + (i & 15) * 8] = qr[j];
    }
  }
  // per-wave k fragments (A operand), L2-resident
  half8 kf[4][2];
  {
    const __half* kb = k16 + ((size_t)(b * N_) + n0 + wv * 32 + col) * H_;
#pragma unroll
    for (int kk = 0; kk < 4; ++kk)
#pragma unroll
      for (int ms = 0; ms < 2; ++ms)
        kf[kk][ms] = *(const half8*)(kb + (size_t)ms * 16 * H_ + kk * 32 + quad * 8);
  }
  __syncthreads();

  // GEMM: rows (quad*4+reg) = n-local, cols (col) = m-local
  f32x4 acc[2][8];
#pragma unroll
  for (int ms = 0; ms < 2; ++ms)
#pragma unroll
    for (int nb = 0; nb < 8; ++nb) acc[ms][nb] = (f32x4){0.f, 0.f, 0.f, 0.f};

#pragma unroll
  for (int kk = 0; kk < 4; ++kk) {
#pragma unroll
    for (int nb = 0; nb < 8; ++nb) {
      half8 bf = *(const half8*)&qa[(nb * 16 + col) * SPB + kk * 32 + quad * 8];
      acc[0][nb] = __builtin_amdgcn_mfma_f32_16x16x32_f16(kf[kk][0], bf, acc[0][nb], 0, 0, 0);
      acc[1][nb] = __builtin_amdgcn_mfma_f32_16x16x32_f16(kf[kk][1], bf, acc[1][nb], 0, 0, 0);
    }
  }
  __syncthreads();  // all qa reads done — buffer now hosts the t-tile

  float lz[8];
#pragma unroll
  for (int nsm = 0; nsm < 8; ++nsm)
    lz[nsm] = __log2f(Z[(size_t)b * M_ + m0 + nsm * 16 + col]);

  float cs[8];
#pragma unroll
  for (int i = 0; i < 8; ++i) cs[i] = 0.f;

#pragma unroll
  for (int msN = 0; msN < 2; ++msN) {
    const int nl = wv * 32 + msN * 16 + quad * 4;  // n-local, 4 consecutive
#pragma unroll
    for (int nsm = 0; nsm < 8; ++nsm) {
      const int ml = nsm * 16 + col;
      const float lzv = lz[nsm];
      const float4 mv = *(const float4*)&mask[((size_t)b * M_ + m0 + ml) * N_ + n0 + nl];
      half4_t h;
#pragma unroll
      for (int reg = 0; reg < 4; ++reg) {
        float mvv = (reg == 0) ? mv.x : (reg == 1) ? mv.y : (reg == 2) ? mv.z : mv.w;
        float x = acc[msN][nsm][reg];
        x = (mvv < 1e-9f) ? -1e9f : x;
        float p = exp2f(x - lzv);
        float t = sqrtf((mvv + 1e-9f) * (p + 1e-9f)) - 1e-9f;
        h[reg] = (_Float16)t;
        cs[msN * 4 + reg] += t;
      }
      *(half4_t*)&qa[ml * SPB + nl] = h;  // scattered LDS write (2-way)
    }
  }
  __syncthreads();  // t-tile complete in LDS

  // coalesced t16 store: full 256 B rows
#pragma unroll
  for (int j = 0; j < 8; ++j) {
    int i = tid + 256 * j;
    int r = i >> 4, u = i & 15;
    *(uint4*)&t16[((size_t)(b * M_) + m0 + r) * N_ + n0 + u * 8] =
        *(const uint4*)&qa[r * SPB + u * 8];
  }

#pragma unroll
  for (int i = 0; i < 8; ++i) {
    cs[i] += __shfl_xor(cs[i], 1);
    cs[i] += __shfl_xor(cs[i], 2);
    cs[i] += __shfl_xor(cs[i], 4);
    cs[i] += __shfl_xor(cs[i], 8);
  }
  if (col == 0) {
#pragma unroll
    for (int i = 0; i < 8; ++i) {
      int n = n0 + wv * 32 + (i >> 2) * 16 + quad * 4 + (i & 3);
      atomicAdd(&colsum[(size_t)b * N_ + n], cs[i]);
    }
  }
}

// ---------------------------------------------------------------------------
// P3.5: invert colsum in place.
// ---------------------------------------------------------------------------
__global__ __launch_bounds__(256) void k_icol(float* __restrict__ cs)
{
  int i = blockIdx.x * 256 + threadIdx.x;
  cs[i] = 1.f / fmaxf(cs[i], 1e-12f);
}

// ---------------------------------------------------------------------------
// P4: u = t * icolsum; out = u / max(rowsum(u),1e-12).
// ---------------------------------------------------------------------------
__global__ __launch_bounds__(256) void k_norm(
    const __half* __restrict__ t16, float* __restrict__ out,
    const float* __restrict__ icol)
{
  const int row = blockIdx.x;
  const int b = row >> 10;
  const half4_t* t4 = (const half4_t*)(t16 + (size_t)row * N_);
  float4* o4 = (float4*)(out + (size_t)row * N_);
  const float4* c4 = (const float4*)(icol + (size_t)b * N_);
  const int tid = threadIdx.x;

  float4 u[4];
  float s = 0.f;
#pragma unroll
  for (int j = 0; j < 4; ++j) {
    int idx = tid + 256 * j;
    half4_t h = t4[idx];
    float4 c = c4[idx];
    u[j].x = (float)h[0] * c.x;
    u[j].y = (float)h[1] * c.y;
    u[j].z = (float)h[2] * c.z;
    u[j].w = (float)h[3] * c.w;
    s += u[j].x + u[j].y + u[j].z + u[j].w;  // t >= 0 so |u| = u
  }
  s += __shfl_xor(s, 1);
  s += __shfl_xor(s, 2);
  s += __shfl_xor(s, 4);
  s += __shfl_xor(s, 8);
  s += __shfl_xor(s, 16);
  s += __shfl_xor(s, 32);
  __shared__ float red[4];
  if ((tid & 63) == 0) red[tid >> 6] = s;
  __syncthreads();
  float tot = red[0] + red[1] + red[2] + red[3];
  float inv = 1.f / fmaxf(tot, 1e-12f);
#pragma unroll
  for (int j = 0; j < 4; ++j) {
    int idx = tid + 256 * j;
    float4 v = u[j];
    v.x *= inv; v.y *= inv; v.z *= inv; v.w *= inv;
    o4[idx] = v;
  }
}

// ---------------------------------------------------------------------------
extern "C" void kernel_launch(void* const* d_in, const int* in_sizes, int n_in,
                              void* d_out, int out_size, void* d_ws, size_t ws_size,
                              hipStream_t stream) {
  const float* cent = (const float*)d_in[0];
  const float* feat = (const float*)d_in[1];
  const float* mask = (const float*)d_in[2];
  const float* Wq = (const float*)d_in[3];
  const float* Wk = (const float*)d_in[4];
  const float* gq = (const float*)d_in[5];
  const float* bq = (const float*)d_in[6];
  const float* mq = (const float*)d_in[7];
  const float* vq = (const float*)d_in[8];
  const float* gk = (const float*)d_in[9];
  const float* bk = (const float*)d_in[10];
  const float* mk = (const float*)d_in[11];
  const float* vk = (const float*)d_in[12];
  float* out = (float*)d_out;

  char* ws = (char*)d_ws;
  // workspace layout (bytes)
  __half* q16  = (__half*)(ws + 0);            //   4,194,304
  __half* k16  = (__half*)(ws + 4194304);      //  16,777,216
  __half* t16  = (__half*)(ws + 20971520);     // 134,217,728
  float* colsum= (float*)(ws + 155189248);     //     262,144
  float* Zr    = (float*)(ws + 155451392);     //      65,536

  // colsum + Z are contiguous: one memset clears both
  hipMemsetAsync(colsum, 0, 262144 + 65536, stream);

  k_embed<<<640, 256, 0, stream>>>(cent, feat, Wq, Wk, gq, bq, mq, vq,
                                   gk, bk, mk, vk, q16, k16);

  dim3 g1(8, 8, 16);  // n-strips of 512 (4 tiles), mt, b -> 1024 wgs
  k_attn1<<<g1, 256, 0, stream>>>(q16, k16, Zr);

  dim3 g3(N_ / 128, M_ / 128, B_);  // (32, 8, 16)
  k_attn3<<<g3, 256, 0, stream>>>(q16, k16, mask, Zr, t16, colsum);
  k_icol<<<B_ * N_ / 256, 256, 0, stream>>>(colsum);
  k_norm<<<B_ * M_, 256, 0, stream>>>(t16, out, colsum);
}

// Round 7
// 607.483 us; speedup vs baseline: 1.1583x; 1.0180x over previous
//
#include <hip/hip_runtime.h>
#include <hip/hip_fp16.h>

#define B_ 16
#define M_ 1024
#define N_ 4096
#define H_ 128
#define CIN_ 67

typedef _Float16 half8 __attribute__((ext_vector_type(8)));
typedef _Float16 half4_t __attribute__((ext_vector_type(4)));
typedef float f32x4 __attribute__((ext_vector_type(4)));

// ---------------------------------------------------------------------------
// P0: q = BN(cent @ Wq^T) * log2(e)  [log2-domain logits], k = BN(feat @ Wk^T).
// ---------------------------------------------------------------------------
#define SPA 104  // 96 + 8 pad, in halfs (row stride)

__global__ __launch_bounds__(256) void k_embed(
    const float* __restrict__ cent, const float* __restrict__ feat,
    const float* __restrict__ Wq, const float* __restrict__ Wk,
    const float* __restrict__ gq, const float* __restrict__ bq,
    const float* __restrict__ mq, const float* __restrict__ vq,
    const float* __restrict__ gk, const float* __restrict__ bk,
    const float* __restrict__ mk, const float* __restrict__ vk,
    __half* __restrict__ q16, __half* __restrict__ k16)
{
  __shared__ __align__(16) __half al[128 * SPA];
  __shared__ __align__(16) __half wl[128 * SPA];
  __shared__ float scl[128], shl[128];

  const int tid = threadIdx.x;
  const int wg  = blockIdx.x;
  const bool isq = (wg < 128);
  const int row0 = isq ? wg * 128 : (wg - 128) * 128;
  const float* in = isq ? cent : feat;
  const float* W  = isq ? Wq : Wk;
  const float* g  = isq ? gq : gk;
  const float* bb = isq ? bq : bk;
  const float* mm = isq ? mq : mk;
  const float* vv = isq ? vq : vk;
  __half* outp = isq ? q16 : k16;

  for (int i = tid; i < 128 * 29; i += 256) {
    int r = i / 29, c = 67 + (i - r * 29);
    al[r * SPA + c] = __float2half(0.f);
    wl[r * SPA + c] = __float2half(0.f);
  }
  for (int i = tid; i < 128 * CIN_; i += 256) {
    int r = i / CIN_, c = i - r * CIN_;
    al[r * SPA + c] = __float2half(in[(size_t)row0 * CIN_ + i]);
    wl[r * SPA + c] = __float2half(W[i]);
  }
  if (tid < 128) {
    float s = g[tid] * rsqrtf(vv[tid] + 1e-5f);
    float sc = isq ? 1.44269504088896f : 1.f;  // fold log2(e) into q
    scl[tid] = s * sc;
    shl[tid] = (bb[tid] - mm[tid] * s) * sc;
  }
  __syncthreads();

  const int lane = tid & 63, wv = tid >> 6;
  const int col = lane & 15, quad = lane >> 4;

  f32x4 acc[2][8];
#pragma unroll
  for (int ms = 0; ms < 2; ++ms)
#pragma unroll
    for (int ns = 0; ns < 8; ++ns) acc[ms][ns] = (f32x4){0.f, 0.f, 0.f, 0.f};

#pragma unroll
  for (int kk = 0; kk < 3; ++kk) {
    half8 af[2], bf[8];
#pragma unroll
    for (int ms = 0; ms < 2; ++ms)
      af[ms] = *(const half8*)&al[(wv * 32 + ms * 16 + col) * SPA + kk * 32 + quad * 8];
#pragma unroll
    for (int ns = 0; ns < 8; ++ns)
      bf[ns] = *(const half8*)&wl[(ns * 16 + col) * SPA + kk * 32 + quad * 8];
#pragma unroll
    for (int ms = 0; ms < 2; ++ms)
#pragma unroll
      for (int ns = 0; ns < 8; ++ns)
        acc[ms][ns] = __builtin_amdgcn_mfma_f32_16x16x32_f16(af[ms], bf[ns], acc[ms][ns], 0, 0, 0);
  }

#pragma unroll
  for (int ms = 0; ms < 2; ++ms)
#pragma unroll
    for (int reg = 0; reg < 4; ++reg) {
      int r = wv * 32 + ms * 16 + quad * 4 + reg;
#pragma unroll
      for (int ns = 0; ns < 8; ++ns) {
        int h = ns * 16 + col;
        float v = acc[ms][ns][reg] * scl[h] + shl[h];
        outp[(size_t)(row0 + r) * H_ + h] = __float2half(v);
      }
    }
}

// ---------------------------------------------------------------------------
// P1: Z[b,m] = sum_n 2^(q.k). Log2-domain logits; padded-LDS k staging with
// prefetch batches interleaved into the exp epilogue halves. (unchanged R6)
// ---------------------------------------------------------------------------
#define SPB 136  // 128 + 8 pad, in halfs

__global__ __launch_bounds__(256, 4) void k_attn1(
    const __half* __restrict__ q16, const __half* __restrict__ k16,
    float* __restrict__ Z)
{
  __shared__ __align__(16) __half ka[128 * SPB];  // 34,816 B

  const int tid = threadIdx.x;
  const int b = blockIdx.z, mt = blockIdx.y, ns = blockIdx.x;
  const int m0 = mt * 128;
  const int lane = tid & 63, wv = tid >> 6;
  const int col = lane & 15, quad = lane >> 4;

  const __half* kstrip = k16 + ((size_t)(b * N_) + ns * 512) * H_;

  {
    uint4 kr[8];
    const uint4* s0 = (const uint4*)kstrip;
#pragma unroll
    for (int j = 0; j < 8; ++j) kr[j] = s0[tid + 256 * j];
#pragma unroll
    for (int j = 0; j < 8; ++j) {
      int i = tid + 256 * j;
      *(uint4*)&ka[(i >> 4) * SPB + (i & 15) * 8] = kr[j];
    }
  }
  half8 qf[4][2];
  {
    const __half* qb = q16 + ((size_t)(b * M_) + m0 + wv * 32 + col) * H_;
#pragma unroll
    for (int kk = 0; kk < 4; ++kk)
#pragma unroll
      for (int ms = 0; ms < 2; ++ms)
        qf[kk][ms] = *(const half8*)(qb + (size_t)ms * 16 * H_ + kk * 32 + quad * 8);
  }
  __syncthreads();

  float zacc[8];
#pragma unroll
  for (int i = 0; i < 8; ++i) zacc[i] = 0.f;

  for (int t = 0; t < 4; ++t) {
    f32x4 acc[2][8];
#pragma unroll
    for (int ms = 0; ms < 2; ++ms)
#pragma unroll
      for (int nb = 0; nb < 8; ++nb) acc[ms][nb] = (f32x4){0.f, 0.f, 0.f, 0.f};

#pragma unroll
    for (int kk = 0; kk < 4; ++kk) {
#pragma unroll
      for (int nb = 0; nb < 8; ++nb) {
        half8 bf = *(const half8*)&ka[(nb * 16 + col) * SPB + kk * 32 + quad * 8];
        acc[0][nb] = __builtin_amdgcn_mfma_f32_16x16x32_f16(qf[kk][0], bf, acc[0][nb], 0, 0, 0);
        acc[1][nb] = __builtin_amdgcn_mfma_f32_16x16x32_f16(qf[kk][1], bf, acc[1][nb], 0, 0, 0);
      }
    }

    const uint4* sn = (const uint4*)(kstrip + (size_t)(t + 1) * 128 * H_);
    uint4 kr2[4];
    if (t < 3) {
      __syncthreads();
#pragma unroll
      for (int j = 0; j < 4; ++j) kr2[j] = sn[tid + 256 * j];
    }

#pragma unroll
    for (int reg = 0; reg < 4; ++reg) {
      float s = 0.f;
#pragma unroll
      for (int nb = 0; nb < 8; ++nb) s += exp2f(acc[0][nb][reg]);
      zacc[reg] += s;
    }

    if (t < 3) {
#pragma unroll
      for (int j = 0; j < 4; ++j) {
        int i = tid + 256 * j;
        *(uint4*)&ka[(i >> 4) * SPB + (i & 15) * 8] = kr2[j];
      }
#pragma unroll
      for (int j = 0; j < 4; ++j) kr2[j] = sn[tid + 256 * (j + 4)];
    }

#pragma unroll
    for (int reg = 0; reg < 4; ++reg) {
      float s = 0.f;
#pragma unroll
      for (int nb = 0; nb < 8; ++nb) s += exp2f(acc[1][nb][reg]);
      zacc[4 + reg] += s;
    }

    if (t < 3) {
#pragma unroll
      for (int j = 0; j < 4; ++j) {
        int i = tid + 256 * (j + 4);
        *(uint4*)&ka[(i >> 4) * SPB + (i & 15) * 8] = kr2[j];
      }
      __syncthreads();
    }
  }

#pragma unroll
  for (int i = 0; i < 8; ++i) {
    zacc[i] += __shfl_xor(zacc[i], 1);
    zacc[i] += __shfl_xor(zacc[i], 2);
    zacc[i] += __shfl_xor(zacc[i], 4);
    zacc[i] += __shfl_xor(zacc[i], 8);
  }
  if (col == 0) {
#pragma unroll
    for (int i = 0; i < 8; ++i) {
      int m = m0 + wv * 32 + (i >> 2) * 16 + quad * 4 + (i & 3);
      atomicAdd(&Z[(size_t)b * M_ + m], zacc[i]);
    }
  }
}

// ---------------------------------------------------------------------------
// P3: BM=64 tile (acc halved -> 20 waves/CU target), 16 KB XOR-swizzled q LDS,
// mask+Z prefetched after GEMM with asm keepalives (forced MLP=8+), epilogue
// pure register compute, t transposed through the same LDS buffer.
// ---------------------------------------------------------------------------
__global__ __launch_bounds__(256, 5) void k_attn3(
    const __half* __restrict__ q16, const __half* __restrict__ k16,
    const float* __restrict__ mask, const float* __restrict__ Z,
    __half* __restrict__ t16, float* __restrict__ colsum)
{
  __shared__ __align__(16) __half qa[64 * 128];  // 16,384 B, swizzled; reused for t

  const int tid = threadIdx.x;
  const int b = blockIdx.z, mt = blockIdx.y, nt = blockIdx.x;
  const int m0 = mt * 64, n0 = nt * 128;
  const int lane = tid & 63, wv = tid >> 6;
  const int col = lane & 15, quad = lane >> 4;

  // stage q-tile (64 rows), swizzled: halfoff c*8 ^ ((row&7)<<3)
  {
    uint4 qr[4];
    const uint4* sq = (const uint4*)(q16 + ((size_t)(b * M_) + m0) * H_);
#pragma unroll
    for (int j = 0; j < 4; ++j) qr[j] = sq[tid + 256 * j];
#pragma unroll
    for (int j = 0; j < 4; ++j) {
      int i = tid + 256 * j;
      int r = i >> 4, c = i & 15;
      *(uint4*)&qa[r * 128 + ((c * 8) ^ ((r & 7) << 3))] = qr[j];
    }
  }
  // per-wave k fragments (A operand: n rows n0 + wv*32 + ms*16 + col)
  half8 kf[4][2];
  {
    const __half* kb = k16 + ((size_t)(b * N_) + n0 + wv * 32 + col) * H_;
#pragma unroll
    for (int kk = 0; kk < 4; ++kk)
#pragma unroll
      for (int ms = 0; ms < 2; ++ms)
        kf[kk][ms] = *(const half8*)(kb + (size_t)ms * 16 * H_ + kk * 32 + quad * 8);
  }
  __syncthreads();

  // GEMM: acc[msN][nb] — rows (quad*4+reg) = n-local, cols (col) = m-local
  f32x4 acc[2][4];
#pragma unroll
  for (int ms = 0; ms < 2; ++ms)
#pragma unroll
    for (int nb = 0; nb < 4; ++nb) acc[ms][nb] = (f32x4){0.f, 0.f, 0.f, 0.f};

#pragma unroll
  for (int kk = 0; kk < 4; ++kk) {
#pragma unroll
    for (int nb = 0; nb < 4; ++nb) {
      int row = nb * 16 + col;
      half8 bf = *(const half8*)&qa[row * 128 + ((kk * 32 + quad * 8) ^ ((col & 7) << 3))];
      acc[0][nb] = __builtin_amdgcn_mfma_f32_16x16x32_f16(kf[kk][0], bf, acc[0][nb], 0, 0, 0);
      acc[1][nb] = __builtin_amdgcn_mfma_f32_16x16x32_f16(kf[kk][1], bf, acc[1][nb], 0, 0, 0);
    }
  }

  // prefetch Z + full mask slice; keepalives force materialization HERE.
  float zr[4];
#pragma unroll
  for (int nsm = 0; nsm < 4; ++nsm)
    zr[nsm] = Z[(size_t)b * M_ + m0 + nsm * 16 + col];
  float4 mv[8];
#pragma unroll
  for (int msN = 0; msN < 2; ++msN) {
    const int nb = n0 + wv * 32 + msN * 16 + quad * 4;
#pragma unroll
    for (int nsm = 0; nsm < 4; ++nsm)
      mv[msN * 4 + nsm] =
          *(const float4*)&mask[((size_t)b * M_ + m0 + nsm * 16 + col) * N_ + nb];
  }
#pragma unroll
  for (int i = 0; i < 8; ++i)
    asm volatile("" : "+v"(mv[i].x), "+v"(mv[i].y), "+v"(mv[i].z), "+v"(mv[i].w));
#pragma unroll
  for (int i = 0; i < 4; ++i) asm volatile("" : "+v"(zr[i]));
  __builtin_amdgcn_sched_barrier(0);

  __syncthreads();  // qa reads done (buffer reused for t); drains prefetches

  float lz[4];
#pragma unroll
  for (int i = 0; i < 4; ++i) lz[i] = __log2f(zr[i]);

  float cs[8];
#pragma unroll
  for (int i = 0; i < 8; ++i) cs[i] = 0.f;

#pragma unroll
  for (int msN = 0; msN < 2; ++msN) {
    const int nl = wv * 32 + msN * 16 + quad * 4;  // n-local, 4 consecutive
#pragma unroll
    for (int nsm = 0; nsm < 4; ++nsm) {
      const int ml = nsm * 16 + col;  // m-local
      const float lzv = lz[nsm];
      const float4 m4 = mv[msN * 4 + nsm];
      half4_t h;
#pragma unroll
      for (int reg = 0; reg < 4; ++reg) {
        float mvv = (reg == 0) ? m4.x : (reg == 1) ? m4.y : (reg == 2) ? m4.z : m4.w;
        float x = acc[msN][nsm][reg];
        x = (mvv < 1e-9f) ? -1e9f : x;
        float p = exp2f(x - lzv);
        float t = sqrtf((mvv + 1e-9f) * (p + 1e-9f)) - 1e-9f;
        h[reg] = (_Float16)t;
        cs[msN * 4 + reg] += t;
      }
      *(half4_t*)&qa[ml * 128 + (nl ^ ((ml & 7) << 3))] = h;
    }
  }

  // overlap cs reduction with other waves' LDS writes
#pragma unroll
  for (int i = 0; i < 8; ++i) {
    cs[i] += __shfl_xor(cs[i], 1);
    cs[i] += __shfl_xor(cs[i], 2);
    cs[i] += __shfl_xor(cs[i], 4);
    cs[i] += __shfl_xor(cs[i], 8);
  }
  __syncthreads();  // t-tile complete in LDS

  // coalesced t16 store: 64 rows x 256 B
#pragma unroll
  for (int j = 0; j < 4; ++j) {
    int i = tid + 256 * j;
    int r = i >> 4, u = i & 15;
    *(uint4*)&t16[((size_t)(b * M_) + m0 + r) * N_ + n0 + u * 8] =
        *(const uint4*)&qa[r * 128 + ((u * 8) ^ ((r & 7) << 3))];
  }

  if (col == 0) {
#pragma unroll
    for (int i = 0; i < 8; ++i) {
      int n = n0 + wv * 32 + (i >> 2) * 16 + quad * 4 + (i & 3);
      atomicAdd(&colsum[(size_t)b * N_ + n], cs[i]);
    }
  }
}

// ---------------------------------------------------------------------------
// P3.5: invert colsum in place.
// ---------------------------------------------------------------------------
__global__ __launch_bounds__(256) void k_icol(float* __restrict__ cs)
{
  int i = blockIdx.x * 256 + threadIdx.x;
  cs[i] = 1.f / fmaxf(cs[i], 1e-12f);
}

// ---------------------------------------------------------------------------
// P4: u = t * icolsum; out = u / max(rowsum(u),1e-12).
// ---------------------------------------------------------------------------
__global__ __launch_bounds__(256) void k_norm(
    const __half* __restrict__ t16, float* __restrict__ out,
    const float* __restrict__ icol)
{
  const int row = blockIdx.x;
  const int b = row >> 10;
  const half4_t* t4 = (const half4_t*)(t16 + (size_t)row * N_);
  float4* o4 = (float4*)(out + (size_t)row * N_);
  const float4* c4 = (const float4*)(icol + (size_t)b * N_);
  const int tid = threadIdx.x;

  float4 u[4];
  float s = 0.f;
#pragma unroll
  for (int j = 0; j < 4; ++j) {
    int idx = tid + 256 * j;
    half4_t h = t4[idx];
    float4 c = c4[idx];
    u[j].x = (float)h[0] * c.x;
    u[j].y = (float)h[1] * c.y;
    u[j].z = (float)h[2] * c.z;
    u[j].w = (float)h[3] * c.w;
    s += u[j].x + u[j].y + u[j].z + u[j].w;  // t >= 0 so |u| = u
  }
  s += __shfl_xor(s, 1);
  s += __shfl_xor(s, 2);
  s += __shfl_xor(s, 4);
  s += __shfl_xor(s, 8);
  s += __shfl_xor(s, 16);
  s += __shfl_xor(s, 32);
  __shared__ float red[4];
  if ((tid & 63) == 0) red[tid >> 6] = s;
  __syncthreads();
  float tot = red[0] + red[1] + red[2] + red[3];
  float inv = 1.f / fmaxf(tot, 1e-12f);
#pragma unroll
  for (int j = 0; j < 4; ++j) {
    int idx = tid + 256 * j;
    float4 v = u[j];
    v.x *= inv; v.y *= inv; v.z *= inv; v.w *= inv;
    o4[idx] = v;
  }
}

// ---------------------------------------------------------------------------
extern "C" void kernel_launch(void* const* d_in, const int* in_sizes, int n_in,
                              void* d_out, int out_size, void* d_ws, size_t ws_size,
                              hipStream_t stream) {
  const float* cent = (const float*)d_in[0];
  const float* feat = (const float*)d_in[1];
  const float* mask = (const float*)d_in[2];
  const float* Wq = (const float*)d_in[3];
  const float* Wk = (const float*)d_in[4];
  const float* gq = (const float*)d_in[5];
  const float* bq = (const float*)d_in[6];
  const float* mq = (const float*)d_in[7];
  const float* vq = (const float*)d_in[8];
  const float* gk = (const float*)d_in[9];
  const float* bk = (const float*)d_in[10];
  const float* mk = (const float*)d_in[11];
  const float* vk = (const float*)d_in[12];
  float* out = (float*)d_out;

  char* ws = (char*)d_ws;
  // workspace layout (bytes)
  __half* q16  = (__half*)(ws + 0);            //   4,194,304
  __half* k16  = (__half*)(ws + 4194304);      //  16,777,216
  __half* t16  = (__half*)(ws + 20971520);     // 134,217,728
  float* colsum= (float*)(ws + 155189248);     //     262,144
  float* Zr    = (float*)(ws + 155451392);     //      65,536

  // colsum + Z are contiguous: one memset clears both
  hipMemsetAsync(colsum, 0, 262144 + 65536, stream);

  k_embed<<<640, 256, 0, stream>>>(cent, feat, Wq, Wk, gq, bq, mq, vq,
                                   gk, bk, mk, vk, q16, k16);

  dim3 g1(8, 8, 16);  // n-strips of 512 (4 tiles), mt, b -> 1024 wgs
  k_attn1<<<g1, 256, 0, stream>>>(q16, k16, Zr);

  dim3 g3(N_ / 128, M_ / 64, B_);  // (32, 16, 16) = 8192 wgs
  k_attn3<<<g3, 256, 0, stream>>>(q16, k16, mask, Zr, t16, colsum);
  k_icol<<<B_ * N_ / 256, 256, 0, stream>>>(colsum);
  k_norm<<<B_ * M_, 256, 0, stream>>>(t16, out, colsum);
}